// Round 19
// baseline (104.580 us; speedup 1.0000x reference)
//
#include <hip/hip_runtime.h>
#include <hip/hip_bf16.h>

// Binarized-weight conv2d: x[32][256][56][56] (f32), W[256][256][3][3] (sign)
// -> out[32][256][56][56] (f32), stride 1, pad 1.
// R19: R11 skeleton, HALF the barriers: 2 K-tiles per barrier period.
//   Period p: {barrier; stage tiles 2p+2,2p+3 -> opposite buf pair (8 GLD);
//   reads+28 MFMA (buf pair A); reads+28 MFMA (buf pair B); vmcnt(0)}.
//   18 periods. vmcnt(0) is issued ~2300 MFMA-cycles after its loads -> free.
//   Prep fused (R17).

#define N_IMG   32
#define C_IN    256
#define C_OUT   256
#define HW      56
#define HP      58
#define PIX     (HW*HW)      // 3136
#define M_TOT   (N_IMG*PIX)  // 100352
#define K_TOT   (C_IN*9)     // 2304

#define WQ_BYTES   (C_OUT * K_TOT)                 // 589824
#define XPAD_BYTES (N_IMG * HP * HP * C_IN)        // 27,557,888
#define WS_NEEDED  (WQ_BYTES + XPAD_BYTES)

#define BM      224
#define NBLK    (M_TOT / BM)   // 448 = 8*56
#define NT      36             // K tiles of 64

#define QCLIP   5.5f

typedef int   i32x4 __attribute__((ext_vector_type(4)));

// ---------------- fused pre-pass (R17):
//   blocks [0,1792): x f32 NCHW -> i8 NHWC padded [n][h+1][w+1][ci], halo fused
//   blocks [1792,2368): W OIHW f32 -> [co][khkw*256+ci] i8 (+-1), 4B packed
#define TPB  (HW * N_IMG)      // 1792 transpose blocks
__global__ void __launch_bounds__(256) prep_kernel(const float* __restrict__ x,
                                                   const float* __restrict__ W,
                                                   signed char* __restrict__ xp,
                                                   unsigned int* __restrict__ wq4) {
    __shared__ __align__(4) signed char s[HW * 260];   // stride 260B (odd dwords)
    const int b = blockIdx.x;
    const int t = threadIdx.x;

    if (b >= TPB) {
        int i4 = (b - TPB) * 256 + t;
        int base = i4 * 4;
        int co = base / K_TOT;
        int k  = base - co * K_TOT;
        int khkw = k >> 8;
        int ci   = k & 255;
        const float* wp = W + co * K_TOT + ci * 9 + khkw;
        unsigned int pk = 0;
        #pragma unroll
        for (int j = 0; j < 4; ++j) {
            unsigned int bb = (wp[j * 9] >= 0.f) ? 0x01u : 0xFFu;
            pk |= bb << (8 * j);
        }
        wq4[i4] = pk;
        return;
    }

    const int h = b % HW;
    const int n = b / HW;
    const float* xrow = x + ((n * C_IN) * HW + h) * HW;
    const float QI = 127.0f / QCLIP;

    #pragma unroll 4
    for (int i = 0; i < 64; ++i) {
        int idx = i * 256 + t;
        int ci = idx >> 6, w = idx & 63;
        if (w < HW) {
            int q = __float2int_rn(xrow[ci * PIX + w] * QI);
            q = q > 127 ? 127 : (q < -127 ? -127 : q);
            s[w * 260 + ci] = (signed char)q;
        }
    }
    __syncthreads();
    unsigned int* xp32 = (unsigned int*)xp;
    #pragma unroll 4
    for (int i = 0; i < 14; ++i) {
        int idx = i * 256 + t;
        int w = idx >> 6, cq = idx & 63;
        unsigned int d = *(const unsigned int*)&s[w * 260 + cq * 4];
        xp32[((n * HP + h + 1) * HP + (w + 1)) * 64 + cq] = d;
    }
    if (t < 64) {
        xp32[((n * HP + h + 1) * HP + 0)  * 64 + t] = 0u;
        xp32[((n * HP + h + 1) * HP + 57) * 64 + t] = 0u;
    }
    if (h == 0) {
        unsigned int* row = xp32 + (unsigned int)(n * HP + 0) * HP * 64;
        for (int i = t; i < HP * 64; i += 256) row[i] = 0u;
    }
    if (h == HW - 1) {
        unsigned int* row = xp32 + (unsigned int)(n * HP + 57) * HP * 64;
        for (int i = t; i < HP * 64; i += 256) row[i] = 0u;
    }
}

// ---------------- i8 GEMM: 4 buffer-regions [256 rows][64B] = 16KB each.
// X at XS(b), W at WS(b). swizzle: 16B chunk c of 64B row at c^((row>>1)&3).
#define XS(b)  ((b)*16384)
#define WS(b)  (65536 + (b)*16384)

__device__ __forceinline__ int xko(int kabs) {       // im2col offset into xpad (i8)
    int khkw = kabs >> 8;                            // 0..8 (uniform)
    int kh = (khkw * 11) >> 5;                       // /3 for 0..8
    int kw = khkw - kh * 3;
    return (kh * HP + kw) * C_IN + (kabs & 255);
}

__global__ void __launch_bounds__(512, 2)
conv_gemm_kernel(const signed char* __restrict__ xpad,
                 const signed char* __restrict__ wq,
                 float* __restrict__ out) {
    __shared__ __align__(16) signed char LDSBUF[131072];   // 128 KiB

    const int t    = threadIdx.x;
    const int lane = t & 63;
    const int wid  = t >> 6;
    const int wpx  = wid >> 2;       // 0..1 : 112-px half
    const int wco  = wid & 3;        // 0..3 : 64-co quarter
    const int l15  = lane & 15;
    const int l4   = lane >> 4;      // 16B k-chunk within 64B row

    int bid = (int)blockIdx.x;
    bid = (bid & 7) * (NBLK / 8) + (bid >> 3);      // XCD swizzle (448 = 8*56)
    const int m0 = bid * BM;

    // read-side LDS byte offsets (within one 16KB region)
    int xrd[7], wrd[4];
    #pragma unroll
    for (int i = 0; i < 7; ++i) {
        int r = wpx * 112 + i * 16 + l15;
        xrd[i] = r * 64 + ((l4 ^ ((r >> 1) & 3)) << 4);
    }
    #pragma unroll
    for (int j = 0; j < 4; ++j) {
        int r = wco * 64 + j * 16 + l15;
        wrd[j] = r * 64 + ((l4 ^ ((r >> 1) & 3)) << 4);
    }

    // stage-side: issue0 -> rows 0..127 (dest t*16), issue1 -> rows 128..255 (+8192)
    const int lc16 = ((t & 3) ^ ((t >> 3) & 3)) << 4;    // inverse-swizzled k offset
    int rbA, rbB;
    {
        int rA = t >> 2;
        int rB = 128 + rA; if (rB > BM - 1) rB = BM - 1;   // rows 224..255: dup, never read
        int mA = m0 + rA, mB = m0 + rB;
        int nA = mA / PIX, pA = mA - nA * PIX, hA = pA / HW, wA = pA - hA * HW;
        int nB = mB / PIX, pB = mB - nB * PIX, hB = pB / HW, wB2 = pB - hB * HW;
        rbA = ((nA * HP + hA) * HP + wA) * C_IN + lc16;
        rbB = ((nB * HP + hB) * HP + wB2) * C_IN + lc16;
    }
    int wgA, wgB;
    {
        int rA = t >> 2;
        wgA = rA * K_TOT + lc16;
        wgB = (128 + rA) * K_TOT + lc16;
    }

#define GLD(gp, off) __builtin_amdgcn_global_load_lds( \
        (const __attribute__((address_space(1))) void*)(gp), \
        (__attribute__((address_space(3))) void*)(LDSBUF + (off)), 16, 0, 0)
#define STGX(b,ko) { GLD(xpad + rbA + (ko), XS(b) + t * 16); \
                     GLD(xpad + rbB + (ko), XS(b) + 8192 + t * 16); }
#define STGW(b,ka) { GLD(wq + wgA + (ka), WS(b) + t * 16); \
                     GLD(wq + wgB + (ka), WS(b) + 8192 + t * 16); }
#define LDXF(i,b)  (*(const i32x4*)(LDSBUF + XS(b) + xrd[i]))
#define LDWF(j,b)  (*(const i32x4*)(LDSBUF + WS(b) + wrd[j]))

    i32x4 acc[7][4];
    #pragma unroll
    for (int i = 0; i < 7; ++i)
        #pragma unroll
        for (int j = 0; j < 4; ++j)
            acc[i][j] = (i32x4){0, 0, 0, 0};

    // One sub-block: read 11 frags from buf cb, 28 MFMA. Compiler emits
    // counted lgkm between reads and MFMAs; SGB overlaps next reads under
    // current MFMAs; the other wave on the SIMD fills the head latency.
#define COMPUTE(cb) { \
        i32x4 xf[7], wf[4]; \
        _Pragma("unroll") \
        for (int i_ = 0; i_ < 7; ++i_) xf[i_] = LDXF(i_, cb); \
        _Pragma("unroll") \
        for (int j_ = 0; j_ < 4; ++j_) wf[j_] = LDWF(j_, cb); \
        _Pragma("unroll") \
        for (int i_ = 0; i_ < 7; ++i_) \
            _Pragma("unroll") \
            for (int j_ = 0; j_ < 4; ++j_) \
                acc[i_][j_] = __builtin_amdgcn_mfma_i32_16x16x64_i8(wf[j_], xf[i_], acc[i_][j_], 0, 0, 0); \
    }

    // Period: [barrier] -> stage 2 tiles into (sb0,sb1) (8 GLD; those bufs'
    // reads were lgkm-complete before the previous period's end) -> compute
    // bufs (cb0,cb1) (staged last period, drained by its vmcnt(0), published
    // by this barrier) -> vmcnt(0) (covered by ~2300 cyc of MFMA above).
    // SGB: {VMEM1,DS3,MFMA8}x7 + {VMEM1,DS1} = 8/22/56.
#define PERIOD(cb0, cb1, sb0, sb1, Ts0, Ts1) { \
        __builtin_amdgcn_sched_barrier(0); \
        __builtin_amdgcn_s_barrier(); \
        __builtin_amdgcn_sched_barrier(0); \
        STGX(sb0, xko((Ts0) * 64)); \
        STGW(sb0, (Ts0) * 64); \
        STGX(sb1, xko((Ts1) * 64)); \
        STGW(sb1, (Ts1) * 64); \
        COMPUTE(cb0); \
        COMPUTE(cb1); \
        _Pragma("unroll") \
        for (int g_ = 0; g_ < 7; ++g_) { \
            __builtin_amdgcn_sched_group_barrier(0x010, 1, 0); \
            __builtin_amdgcn_sched_group_barrier(0x100, 3, 0); \
            __builtin_amdgcn_sched_group_barrier(0x008, 8, 0); \
        } \
        __builtin_amdgcn_sched_group_barrier(0x010, 1, 0); \
        __builtin_amdgcn_sched_group_barrier(0x100, 1, 0); \
        asm volatile("s_waitcnt vmcnt(0)" ::: "memory"); \
        __builtin_amdgcn_sched_barrier(0); \
    }

    // prologue: stage tiles 0 -> buf0, 1 -> buf1 (8 GLD); drain; barrier.
    STGX(0, xko(0));   STGW(0, 0);
    STGX(1, xko(64));  STGW(1, 64);
    asm volatile("s_waitcnt vmcnt(0)" ::: "memory");
    __builtin_amdgcn_sched_barrier(0);
    __builtin_amdgcn_s_barrier();
    __builtin_amdgcn_sched_barrier(0);

    #pragma unroll 1
    for (int it = 0; it < 9; ++it) {
        const int Tb = 4 * it;
        int s2 = Tb + 2; if (s2 > NT - 1) s2 = NT - 1;
        int s3 = Tb + 3; if (s3 > NT - 1) s3 = NT - 1;
        int s4 = Tb + 4; if (s4 > NT - 1) s4 = NT - 1;   // clamped over-stage
        int s5 = Tb + 5; if (s5 > NT - 1) s5 = NT - 1;
        PERIOD(0, 1, 2, 3, s2, s3);    // computes tiles Tb, Tb+1
        PERIOD(2, 3, 0, 1, s4, s5);    // computes tiles Tb+2, Tb+3
    }

    // epilogue: C row=co (l4*4+r), col=px (l15); dequant by QCLIP/127
    const float QS = QCLIP / 127.0f;
    const int nimg = m0 / PIX;                // exact: 3136 = 14*224
    const int p0   = m0 - nimg * PIX;
    float* ob = out + nimg * (C_OUT * PIX);
    #pragma unroll
    for (int i = 0; i < 7; ++i) {
        int p = p0 + wpx * 112 + i * 16 + l15;
        #pragma unroll
        for (int j = 0; j < 4; ++j) {
            int co = wco * 64 + j * 16 + l4 * 4;
            #pragma unroll
            for (int r = 0; r < 4; ++r)
                ob[(co + r) * PIX + p] = (float)acc[i][j][r] * QS;
        }
    }
#undef PERIOD
#undef COMPUTE
#undef GLD
#undef STGX
#undef STGW
#undef LDXF
#undef LDWF
}

// ---------------- fallback: naive direct conv
__global__ void __launch_bounds__(256) conv_naive_kernel(const float* __restrict__ x,
                                                         const float* __restrict__ W,
                                                         float* __restrict__ out) {
    int idx = blockIdx.x * 256 + threadIdx.x;
    int w = idx % HW;
    int tmp = idx / HW;
    int h = tmp % HW;
    tmp /= HW;
    int co = tmp & 255;
    int n  = tmp >> 8;
    const float* xn = x + n * (C_IN * PIX);
    const float* wc = W + co * K_TOT;
    float acc = 0.f;
    for (int ci = 0; ci < C_IN; ++ci) {
        const float* xc = xn + ci * PIX;
        const float* wk = wc + ci * 9;
        #pragma unroll
        for (int kh = 0; kh < 3; ++kh) {
            int hh = h + kh - 1;
            if (hh < 0 || hh >= HW) continue;
            #pragma unroll
            for (int kw = 0; kw < 3; ++kw) {
                int ww = w + kw - 1;
                if (ww < 0 || ww >= HW) continue;
                float xv = xc[hh * HW + ww];
                acc += (wk[kh * 3 + kw] >= 0.f) ? xv : -xv;
            }
        }
    }
    out[idx] = acc;
}

extern "C" void kernel_launch(void* const* d_in, const int* in_sizes, int n_in,
                              void* d_out, int out_size, void* d_ws, size_t ws_size,
                              hipStream_t stream) {
    const float* x = (const float*)d_in[0];
    const float* W = (const float*)d_in[1];
    float* out = (float*)d_out;

    if (ws_size < (size_t)WS_NEEDED) {
        int total = N_IMG * C_OUT * PIX;
        conv_naive_kernel<<<(total + 255) / 256, 256, 0, stream>>>(x, W, out);
        return;
    }

    unsigned int* wq4   = (unsigned int*)d_ws;
    signed char*  xpad  = (signed char*)d_ws + WQ_BYTES;

    prep_kernel<<<TPB + WQ_BYTES / 4 / 256, 256, 0, stream>>>(x, W, xpad, wq4);
    conv_gemm_kernel<<<dim3(NBLK), 512, 0, stream>>>(xpad, (const signed char*)wq4, out);
}

// Round 20
// 96.490 us; speedup vs baseline: 1.0838x; 1.0838x over previous
//
#include <hip/hip_runtime.h>
#include <hip/hip_bf16.h>

// Binarized-weight conv2d: x[32][256][56][56] (f32), W[256][256][3][3] (sign)
// -> out[32][256][56][56] (f32), stride 1, pad 1.
// R20 = R17 (best verified: 96.9us total). GEMM = R11 (best of 13 structural
//   variants: 72us; i8, 4-buffer pipeline, vmcnt(4), SGB 4/11/28, one
//   barrier/tile). Prep fused: transpose+quant (1792 blocks) + W binarize
//   (576 blocks) in one launch, HBM-floor bound.

#define N_IMG   32
#define C_IN    256
#define C_OUT   256
#define HW      56
#define HP      58
#define PIX     (HW*HW)      // 3136
#define M_TOT   (N_IMG*PIX)  // 100352
#define K_TOT   (C_IN*9)     // 2304

#define WQ_BYTES   (C_OUT * K_TOT)                 // 589824
#define XPAD_BYTES (N_IMG * HP * HP * C_IN)        // 27,557,888
#define WS_NEEDED  (WQ_BYTES + XPAD_BYTES)

#define BM      224
#define NBLK    (M_TOT / BM)   // 448 = 8*56
#define NT      36             // K tiles of 64

#define QCLIP   5.5f

typedef int   i32x4 __attribute__((ext_vector_type(4)));

// ---------------- fused pre-pass:
//   blocks [0,1792): x f32 NCHW -> i8 NHWC padded [n][h+1][w+1][ci], halo fused
//   blocks [1792,2368): W OIHW f32 -> [co][khkw*256+ci] i8 (+-1), 4B packed
#define TPB  (HW * N_IMG)      // 1792 transpose blocks
__global__ void __launch_bounds__(256) prep_kernel(const float* __restrict__ x,
                                                   const float* __restrict__ W,
                                                   signed char* __restrict__ xp,
                                                   unsigned int* __restrict__ wq4) {
    __shared__ __align__(4) signed char s[HW * 260];   // stride 260B (odd dwords)
    const int b = blockIdx.x;
    const int t = threadIdx.x;

    if (b >= TPB) {
        // ---- W binarize: 576 blocks x 256 threads over 147456 dwords ----
        int i4 = (b - TPB) * 256 + t;
        int base = i4 * 4;
        int co = base / K_TOT;
        int k  = base - co * K_TOT;
        int khkw = k >> 8;
        int ci   = k & 255;
        const float* wp = W + co * K_TOT + ci * 9 + khkw;
        unsigned int pk = 0;
        #pragma unroll
        for (int j = 0; j < 4; ++j) {
            unsigned int bb = (wp[j * 9] >= 0.f) ? 0x01u : 0xFFu;
            pk |= bb << (8 * j);
        }
        wq4[i4] = pk;
        return;
    }

    // ---- transpose + quantize ----
    const int h = b % HW;
    const int n = b / HW;
    const float* xrow = x + ((n * C_IN) * HW + h) * HW;
    const float QI = 127.0f / QCLIP;

    #pragma unroll 4
    for (int i = 0; i < 64; ++i) {
        int idx = i * 256 + t;
        int ci = idx >> 6, w = idx & 63;
        if (w < HW) {
            int q = __float2int_rn(xrow[ci * PIX + w] * QI);
            q = q > 127 ? 127 : (q < -127 ? -127 : q);
            s[w * 260 + ci] = (signed char)q;
        }
    }
    __syncthreads();
    unsigned int* xp32 = (unsigned int*)xp;
    #pragma unroll 4
    for (int i = 0; i < 14; ++i) {
        int idx = i * 256 + t;                        // dword over 56*64
        int w = idx >> 6, cq = idx & 63;
        unsigned int d = *(const unsigned int*)&s[w * 260 + cq * 4];
        xp32[((n * HP + h + 1) * HP + (w + 1)) * 64 + cq] = d;
    }
    // fused halo zeros
    if (t < 64) {
        xp32[((n * HP + h + 1) * HP + 0)  * 64 + t] = 0u;
        xp32[((n * HP + h + 1) * HP + 57) * 64 + t] = 0u;
    }
    if (h == 0) {
        unsigned int* row = xp32 + (unsigned int)(n * HP + 0) * HP * 64;
        for (int i = t; i < HP * 64; i += 256) row[i] = 0u;
    }
    if (h == HW - 1) {
        unsigned int* row = xp32 + (unsigned int)(n * HP + 57) * HP * 64;
        for (int i = t; i < HP * 64; i += 256) row[i] = 0u;
    }
}

// ---------------- i8 GEMM (R11): 4 buffer-regions [256 rows][64B] = 16KB each.
// X at XS(b), W at WS(b). swizzle: 16B chunk c of 64B row at c^((row>>1)&3).
#define XS(b)  ((b)*16384)
#define WS(b)  (65536 + (b)*16384)

__device__ __forceinline__ int xko(int kabs) {       // im2col offset into xpad (i8)
    int khkw = kabs >> 8;                            // 0..8 (uniform)
    int kh = (khkw * 11) >> 5;                       // /3 for 0..8
    int kw = khkw - kh * 3;
    return (kh * HP + kw) * C_IN + (kabs & 255);
}

__global__ void __launch_bounds__(512, 2)
conv_gemm_kernel(const signed char* __restrict__ xpad,
                 const signed char* __restrict__ wq,
                 float* __restrict__ out) {
    __shared__ __align__(16) signed char LDSBUF[131072];   // 128 KiB

    const int t    = threadIdx.x;
    const int lane = t & 63;
    const int wid  = t >> 6;
    const int wpx  = wid >> 2;       // 0..1 : 112-px half
    const int wco  = wid & 3;        // 0..3 : 64-co quarter
    const int l15  = lane & 15;
    const int l4   = lane >> 4;      // 16B k-chunk within 64B row

    int bid = (int)blockIdx.x;
    bid = (bid & 7) * (NBLK / 8) + (bid >> 3);      // XCD swizzle (448 = 8*56)
    const int m0 = bid * BM;

    // read-side LDS byte offsets (within one 16KB region)
    int xrd[7], wrd[4];
    #pragma unroll
    for (int i = 0; i < 7; ++i) {
        int r = wpx * 112 + i * 16 + l15;
        xrd[i] = r * 64 + ((l4 ^ ((r >> 1) & 3)) << 4);
    }
    #pragma unroll
    for (int j = 0; j < 4; ++j) {
        int r = wco * 64 + j * 16 + l15;
        wrd[j] = r * 64 + ((l4 ^ ((r >> 1) & 3)) << 4);
    }

    // stage-side: issue0 -> rows 0..127 (dest t*16), issue1 -> rows 128..255 (+8192)
    const int lc16 = ((t & 3) ^ ((t >> 3) & 3)) << 4;    // inverse-swizzled k offset
    int rbA, rbB;
    {
        int rA = t >> 2;
        int rB = 128 + rA; if (rB > BM - 1) rB = BM - 1;   // rows 224..255: dup, never read
        int mA = m0 + rA, mB = m0 + rB;
        int nA = mA / PIX, pA = mA - nA * PIX, hA = pA / HW, wA = pA - hA * HW;
        int nB = mB / PIX, pB = mB - nB * PIX, hB = pB / HW, wB2 = pB - hB * HW;
        rbA = ((nA * HP + hA) * HP + wA) * C_IN + lc16;
        rbB = ((nB * HP + hB) * HP + wB2) * C_IN + lc16;
    }
    int wgA, wgB;
    {
        int rA = t >> 2;
        wgA = rA * K_TOT + lc16;
        wgB = (128 + rA) * K_TOT + lc16;
    }

#define GLD(gp, off) __builtin_amdgcn_global_load_lds( \
        (const __attribute__((address_space(1))) void*)(gp), \
        (__attribute__((address_space(3))) void*)(LDSBUF + (off)), 16, 0, 0)
#define STGX(b,ko) { GLD(xpad + rbA + (ko), XS(b) + t * 16); \
                     GLD(xpad + rbB + (ko), XS(b) + 8192 + t * 16); }
#define STGW(b,ka) { GLD(wq + wgA + (ka), WS(b) + t * 16); \
                     GLD(wq + wgB + (ka), WS(b) + 8192 + t * 16); }
#define LDXF(i,b)  (*(const i32x4*)(LDSBUF + XS(b) + xrd[i]))
#define LDWF(j,b)  (*(const i32x4*)(LDSBUF + WS(b) + wrd[j]))

    i32x4 acc[7][4];
    #pragma unroll
    for (int i = 0; i < 7; ++i)
        #pragma unroll
        for (int j = 0; j < 4; ++j)
            acc[i][j] = (i32x4){0, 0, 0, 0};

    i32x4 xfA[7], wfA[4], xfB[7], wfB[4];

    // Per tile t (buffer b=t&3): [barrier] then ONE scheduling region:
    //   stage tile t+3 (4 GLD) | ds_reads frags(t+1) | 28 MFMA(t) | vmcnt(4).
    //   reads(t+1) staged at t-2, retired by vmcnt(4)@t-1 (outstanding 4 =
    //   t+2's stages only), published by this tile's top barrier.
#define TILE(j, XU, WU, XD, WD) { \
        int Ts = Tb + (j) + 3; if (Ts > NT - 1) Ts = NT - 1; \
        __builtin_amdgcn_sched_barrier(0); \
        __builtin_amdgcn_s_barrier(); \
        __builtin_amdgcn_sched_barrier(0); \
        STGX(((j) + 3) & 3, xko(Ts * 64)); \
        STGW(((j) + 3) & 3, Ts * 64); \
        _Pragma("unroll") \
        for (int i_ = 0; i_ < 7; ++i_) XD[i_] = LDXF(i_, ((j) + 1) & 3); \
        _Pragma("unroll") \
        for (int j_ = 0; j_ < 4; ++j_) WD[j_] = LDWF(j_, ((j) + 1) & 3); \
        _Pragma("unroll") \
        for (int i_ = 0; i_ < 7; ++i_) \
            _Pragma("unroll") \
            for (int j_ = 0; j_ < 4; ++j_) \
                acc[i_][j_] = __builtin_amdgcn_mfma_i32_16x16x64_i8(WU[j_], XU[i_], acc[i_][j_], 0, 0, 0); \
        _Pragma("unroll") \
        for (int g_ = 0; g_ < 3; ++g_) { \
            __builtin_amdgcn_sched_group_barrier(0x010, 1, 0); \
            __builtin_amdgcn_sched_group_barrier(0x100, 3, 0); \
            __builtin_amdgcn_sched_group_barrier(0x008, 7, 0); \
        } \
        __builtin_amdgcn_sched_group_barrier(0x010, 1, 0); \
        __builtin_amdgcn_sched_group_barrier(0x100, 2, 0); \
        __builtin_amdgcn_sched_group_barrier(0x008, 7, 0); \
        asm volatile("s_waitcnt vmcnt(4)" ::: "memory"); \
    }

    // prologue: stage tiles 0,1,2 (12 GLD); vmcnt(4) retires tiles 0 AND 1
    // fully (outstanding 4 = tile 2's stages); barrier publishes; read frags(0).
    STGX(0, xko(0));   STGW(0, 0);
    STGX(1, xko(64));  STGW(1, 64);
    STGX(2, xko(128)); STGW(2, 128);
    asm volatile("s_waitcnt vmcnt(4)" ::: "memory");
    __builtin_amdgcn_sched_barrier(0);
    __builtin_amdgcn_s_barrier();
    __builtin_amdgcn_sched_barrier(0);
    #pragma unroll
    for (int i = 0; i < 7; ++i) xfA[i] = LDXF(i, 0);
    #pragma unroll
    for (int j = 0; j < 4; ++j) wfA[j] = LDWF(j, 0);

    #pragma unroll 1
    for (int it = 0; it < 9; ++it) {
        const int Tb = 4 * it;
        TILE(0, xfA, wfA, xfB, wfB);
        TILE(1, xfB, wfB, xfA, wfA);
        TILE(2, xfA, wfA, xfB, wfB);
        TILE(3, xfB, wfB, xfA, wfA);
    }
    asm volatile("s_waitcnt vmcnt(0)" ::: "memory");   // drain stage GLDs (LDS freed at exit)

    // epilogue: C row=co (l4*4+r), col=px (l15); dequant by QCLIP/127
    const float QS = QCLIP / 127.0f;
    const int nimg = m0 / PIX;                // exact: 3136 = 14*224
    const int p0   = m0 - nimg * PIX;
    float* ob = out + nimg * (C_OUT * PIX);
    #pragma unroll
    for (int i = 0; i < 7; ++i) {
        int p = p0 + wpx * 112 + i * 16 + l15;
        #pragma unroll
        for (int j = 0; j < 4; ++j) {
            int co = wco * 64 + j * 16 + l4 * 4;
            #pragma unroll
            for (int r = 0; r < 4; ++r)
                ob[(co + r) * PIX + p] = (float)acc[i][j][r] * QS;
        }
    }
#undef TILE
#undef GLD
#undef STGX
#undef STGW
#undef LDXF
#undef LDWF
}

// ---------------- fallback: naive direct conv
__global__ void __launch_bounds__(256) conv_naive_kernel(const float* __restrict__ x,
                                                         const float* __restrict__ W,
                                                         float* __restrict__ out) {
    int idx = blockIdx.x * 256 + threadIdx.x;
    int w = idx % HW;
    int tmp = idx / HW;
    int h = tmp % HW;
    tmp /= HW;
    int co = tmp & 255;
    int n  = tmp >> 8;
    const float* xn = x + n * (C_IN * PIX);
    const float* wc = W + co * K_TOT;
    float acc = 0.f;
    for (int ci = 0; ci < C_IN; ++ci) {
        const float* xc = xn + ci * PIX;
        const float* wk = wc + ci * 9;
        #pragma unroll
        for (int kh = 0; kh < 3; ++kh) {
            int hh = h + kh - 1;
            if (hh < 0 || hh >= HW) continue;
            #pragma unroll
            for (int kw = 0; kw < 3; ++kw) {
                int ww = w + kw - 1;
                if (ww < 0 || ww >= HW) continue;
                float xv = xc[hh * HW + ww];
                acc += (wk[kh * 3 + kw] >= 0.f) ? xv : -xv;
            }
        }
    }
    out[idx] = acc;
}

extern "C" void kernel_launch(void* const* d_in, const int* in_sizes, int n_in,
                              void* d_out, int out_size, void* d_ws, size_t ws_size,
                              hipStream_t stream) {
    const float* x = (const float*)d_in[0];
    const float* W = (const float*)d_in[1];
    float* out = (float*)d_out;

    if (ws_size < (size_t)WS_NEEDED) {
        int total = N_IMG * C_OUT * PIX;
        conv_naive_kernel<<<(total + 255) / 256, 256, 0, stream>>>(x, W, out);
        return;
    }

    unsigned int* wq4   = (unsigned int*)d_ws;
    signed char*  xpad  = (signed char*)d_ws + WQ_BYTES;

    prep_kernel<<<TPB + WQ_BYTES / 4 / 256, 256, 0, stream>>>(x, W, xpad, wq4);
    conv_gemm_kernel<<<dim3(NBLK), 512, 0, stream>>>(xpad, (const signed char*)wq4, out);
}